// Round 1
// baseline (874.264 us; speedup 1.0000x reference)
//
#include <hip/hip_runtime.h>

// ProdLayer v2: out[nids[p]] = sum_j node_mars[cids[p][j]]   (B=128 floats/row)
//
// v1 (868 us) gave each 32-lane group one node: dependent index-load ->
// 4-gather chain per node, ~2 serial memory epochs/node, only 64B/lane of
// gather lookahead => latency-pipeline-bound at ~1.5 TB/s vs 6.3 achievable.
// v2: each group owns 32 consecutive products; indices for all 32 staged
// once via fully-coalesced loads into LDS (same-wave, no barrier), then a
// pure gather loop with 16 independent gathers in flight (#pragma unroll 4),
// nontemporal output stores so the 256MB write stream doesn't evict
// node_mars from L2/L3.

#define B4  32   // float4 chunks per row (B=128)
#define NPG 32   // products per 32-lane group
#define GPB 8    // groups per 256-thread block

typedef float fvec4 __attribute__((ext_vector_type(4)));

__global__ __launch_bounds__(256, 4) void prod_layer_kernel(
    const float4* __restrict__ nm,      // node_mars, [N_SRC][32] float4
    const float4* __restrict__ em,      // element_mars (input), row 0 is the reserved row
    const int*    __restrict__ nids,    // [N_PROD]
    const int4*   __restrict__ cids,    // [N_PROD] (4 children packed)
    float4*       __restrict__ out,     // [N_PROD+1][32] float4
    int n_prod)
{
    __shared__ int4 s_cids[GPB][NPG];
    __shared__ int  s_dst [GPB][NPG];

    const int grp  = threadIdx.x >> 5;   // group within block
    const int lane = threadIdx.x & 31;   // float4 chunk within row
    const int g    = blockIdx.x * GPB + grp;

    const int n_groups = (n_prod + NPG - 1) / NPG;

    if (g >= n_groups) {
        // one extra group copies reserved row 0 from element_mars
        if (g == n_groups) out[lane] = em[lane];
        return;
    }

    const int pbase = g * NPG;
    const int cnt   = min(NPG, n_prod - pbase);

    // Stage 32 products' indices with fully-coalesced loads:
    // 512B of cids + 128B of nids per group.
    if (lane < cnt) {
        s_cids[grp][lane] = cids[pbase + lane];
        s_dst [grp][lane] = nids[pbase + lane];
    }
    // Producer and consumers are the same 32 lanes (same wave): DS ops from
    // one wave execute in order; wave_barrier just pins compiler scheduling.
    __builtin_amdgcn_wave_barrier();

    #pragma unroll 4
    for (int j = 0; j < cnt; ++j) {
        const int4 c   = s_cids[grp][j];   // LDS broadcast read
        const int  dst = s_dst [grp][j];

        // Four coalesced 512B row-gathers (32 lanes x 16B contiguous each)
        float4 a = nm[c.x * B4 + lane];
        float4 b = nm[c.y * B4 + lane];
        float4 d = nm[c.z * B4 + lane];
        float4 e = nm[c.w * B4 + lane];

        float4 s;
        s.x = (a.x + b.x) + (d.x + e.x);
        s.y = (a.y + b.y) + (d.y + e.y);
        s.z = (a.z + b.z) + (d.z + e.z);
        s.w = (a.w + b.w) + (d.w + e.w);

        // Streaming output: bypass cache allocation, keep L2/L3 for node_mars.
        __builtin_nontemporal_store(*(const fvec4*)&s, (fvec4*)&out[dst * B4 + lane]);
    }
}

extern "C" void kernel_launch(void* const* d_in, const int* in_sizes, int n_in,
                              void* d_out, int out_size, void* d_ws, size_t ws_size,
                              hipStream_t stream) {
    const float4* nm   = (const float4*)d_in[0];
    const float4* em   = (const float4*)d_in[1];
    const int*    nids = (const int*)d_in[2];
    const int4*   cids = (const int4*)d_in[3];
    float4*       out  = (float4*)d_out;

    const int n_prod   = in_sizes[2];                    // 500,000
    const int n_groups = (n_prod + NPG - 1) / NPG;
    const int total_g  = n_groups + 1;                   // +1 group for row 0
    const int block    = 256;
    const int grid     = (total_g + GPB - 1) / GPB;

    prod_layer_kernel<<<grid, block, 0, stream>>>(nm, em, nids, cids, out, n_prod);
}